// Round 13
// baseline (201.807 us; speedup 1.0000x reference)
//
#include <hip/hip_runtime.h>

#define NNODES 10000
#define MP 10112            // 632 * 16 GEMM M-tiles
#define F 256
#define H 512
#define CAP 128             // bucket capacity; Poisson(32) tail @128 ~ 1e-40

typedef _Float16 half8 __attribute__((ext_vector_type(8)));
typedef float floatx4 __attribute__((ext_vector_type(4)));
typedef float floatx8 __attribute__((ext_vector_type(8)));

// ---------- prep: zero cnt + W1^T + W2^T + x->f16 (1250 blocks) ----------
__global__ __launch_bounds__(256) void prep_k(const float* __restrict__ W1,
                                              const float* __restrict__ W2,
                                              const float* __restrict__ x,
                                              _Float16* __restrict__ W1t,
                                              _Float16* __restrict__ W2t,
                                              _Float16* __restrict__ xh,
                                              int* __restrict__ cnt) {
  int gt = blockIdx.x * 256 + threadIdx.x;
  if (gt < NNODES) cnt[gt] = 0;
  if (gt < H * F) {
    W1t[gt] = (_Float16)W1[(gt & 255) * H + (gt >> 8)];
    W2t[gt] = (_Float16)W2[(gt & 511) * F + (gt >> 9)];
  }
  if (gt < NNODES * F / 8) {
    floatx8 v = *(const floatx8*)(x + (size_t)gt * 8);
    *(half8*)(xh + (size_t)gt * 8) = __builtin_convertvector(v, half8);
  }
}

// ---------- bucket CSR build: one pass, cnt ends as degree ----------
__global__ __launch_bounds__(256) void build_k(const int* __restrict__ src,
                                               const int* __restrict__ dst,
                                               int* __restrict__ cnt,
                                               int* __restrict__ csr, int E) {
  int e = blockIdx.x * blockDim.x + threadIdx.x;
  if (e < E) {
    int d = dst[e];
    int p = atomicAdd(&cnt[d], 1);
    if (p < CAP) csr[(size_t)d * CAP + p] = src[e];
  }
}

// ---------- half-wave-per-node aggregation over f16 rows (F=256) ----------
template <bool FUSE_MAX>
__global__ __launch_bounds__(256) void aggb_k(const _Float16* __restrict__ in,
                                              const int* __restrict__ cnt,
                                              const int* __restrict__ csr,
                                              const float* __restrict__ bias,
                                              _Float16* __restrict__ outh,
                                              float* __restrict__ out) {
  __shared__ float smem[2048];
  int tid = threadIdx.x;
  int lane = tid & 63, wvi = tid >> 6;
  int half = lane >> 5, hl = lane & 31;
  int f0 = hl * 8;
  int node = (blockIdx.x * 4 + wvi) * 2 + half;   // grid 1250 -> node < 10000
  floatx8 bb = {};
  if (FUSE_MAX) bb = *(const floatx8*)(bias + f0);
  int deg = min(cnt[node], CAP);
  float di = rsqrtf((float)(deg + 1));
  const int* bucket = csr + (size_t)node * CAP;
  floatx8 acc = {};
  for (int c = 0; c < deg; c += 32) {
    int mm = min(32, deg - c);
    int sv = 0; float wvv = 0.f;
    if (hl < mm) {
      sv = bucket[c + hl];
      wvv = rsqrtf((float)(cnt[sv] + 1));
    }
    #pragma unroll
    for (int b = 0; b < 2; b++) {
      int base = b * 16;
      if (base < mm) {
        int sj[16]; float wj[16];
        #pragma unroll
        for (int u = 0; u < 16; u++) {
          int l = (half << 5) | (base + u);
          sj[u] = __shfl(sv, l, 64);
          wj[u] = __shfl(wvv, l, 64);
        }
        half8 hv[16];
        #pragma unroll
        for (int u = 0; u < 16; u++)
          hv[u] = *(const half8*)(in + (size_t)sj[u] * F + f0);
        #pragma unroll
        for (int u = 0; u < 16; u++)
          acc += wj[u] * __builtin_convertvector(hv[u], floatx8);
      }
    }
  }
  half8 xsv = *(const half8*)(in + (size_t)node * F + f0);
  floatx8 tot = di * acc + (di * di) * __builtin_convertvector(xsv, floatx8);
  if (FUSE_MAX) {
    tot += bb;
    floatx8 lmax;
    #pragma unroll
    for (int t = 0; t < 8; t++) lmax[t] = fmaxf(tot[t], 0.f);
    float* srow = smem + (size_t)(wvi * 2 + half) * 256;
    *(floatx8*)(srow + f0) = lmax;
    __syncthreads();
    float m = smem[tid];
    #pragma unroll
    for (int r = 1; r < 8; r++) m = fmaxf(m, smem[r * 256 + tid]);
    // relu outputs >= 0; out poison/zero is <= 0 as int -> atomicMax correct
    atomicMax((int*)&out[tid], __float_as_int(m));
  } else {
    *(half8*)(outh + (size_t)node * F + f0) = __builtin_convertvector(tot, half8);
  }
}

// ---------- thin high-TLP GEMM: C(MP x NT) = A(MP x K) @ Bt(NT x K)^T ----------
// R12: the fused gemm12 was occupancy-starved BY GRID (632 blocks = 2.5/CU,
// Occ 16%, ~50us across R8-R11 regardless of ILP tricks) because fusion
// forces each block to produce all 512 h1 cols. Unfused thin tiles:
// wave = 16x32 (acc 8 VGPR, 3 loads/k-step, no LDS), block = 4 waves =
// 16x128 cols. gemm1 grid 2528 (9.9 blk/CU), gemm2 1264 (4.9) -> ~32
// waves/CU, ~100 loads in flight/CU: same high-TLP L2-stream regime the
// agg kernels prove out (~160MB from L2 in <10us). Weight traffic is
// invariant to this N-split (each 16-row M-group reads full W either way).
template <int K, int NT, bool RELU>
__global__ __launch_bounds__(256) void gemmthin_k(const _Float16* __restrict__ A,
                                                  const _Float16* __restrict__ Bt,
                                                  const float* __restrict__ bias,
                                                  _Float16* __restrict__ C) {
  int lane = threadIdx.x & 63;
  int wv = threadIdx.x >> 6;
  int r = lane & 15, q = lane >> 4;
  int m0 = blockIdx.x * 16;
  int n0 = blockIdx.y * 128 + wv * 32;
  floatx4 acc[2] = {};
  const _Float16* Ap = A + (size_t)(m0 + r) * K + q * 8;
  const _Float16* Bp = Bt + (size_t)(n0 + r) * K + q * 8;
  for (int k0 = 0; k0 < K; k0 += 32) {
    half8 a  = *(const half8*)(Ap + k0);
    half8 b0 = *(const half8*)(Bp + k0);
    half8 b1 = *(const half8*)(Bp + 16 * K + k0);
    acc[0] = __builtin_amdgcn_mfma_f32_16x16x32_f16(a, b0, acc[0], 0, 0, 0);
    acc[1] = __builtin_amdgcn_mfma_f32_16x16x32_f16(a, b1, acc[1], 0, 0, 0);
  }
  #pragma unroll
  for (int j = 0; j < 2; j++) {
    int n = n0 + j * 16 + r;
    float bv = RELU ? bias[n] : 0.f;
    #pragma unroll
    for (int rr = 0; rr < 4; rr++) {
      int row = m0 + q * 4 + rr;
      float v = acc[j][rr] + bv;
      if (RELU) v = fmaxf(v, 0.f);
      C[(size_t)row * NT + n] = (_Float16)v;
    }
  }
}

extern "C" void kernel_launch(void* const* d_in, const int* in_sizes, int n_in,
                              void* d_out, int out_size, void* d_ws, size_t ws_size,
                              hipStream_t stream) {
  const float* x  = (const float*)d_in[0];
  const int*   ei = (const int*)d_in[1];
  const float* W1 = (const float*)d_in[2];
  const float* b1 = (const float*)d_in[3];
  const float* W2 = (const float*)d_in[4];
  const float* b2 = (const float*)d_in[5];
  const int E = in_sizes[1] / 2;
  const int N = NNODES;
  const int* src = ei;
  const int* dst = ei + E;

  char* w = (char*)d_ws;
  size_t off = 0;
  auto take = [&](size_t bytes) -> void* {
    void* p = w + off;
    off += (bytes + 255) & ~(size_t)255;
    return p;
  };
  int*       cnt    = (int*)take((size_t)N * 4);
  int*       csr    = (int*)take((size_t)N * CAP * 4);
  _Float16*  W1t    = (_Float16*)take((size_t)H * F * 2);
  _Float16*  W2t    = (_Float16*)take((size_t)F * H * 2);
  _Float16*  xh     = (_Float16*)take((size_t)N * F * 2);
  _Float16*  axh    = (_Float16*)take((size_t)MP * F * 2);   // padded M
  _Float16*  h1h    = (_Float16*)take((size_t)MP * H * 2);   // padded M
  _Float16*  xw2h   = (_Float16*)take((size_t)MP * F * 2);   // padded M

  prep_k<<<1250, 256, 0, stream>>>(W1, W2, x, W1t, W2t, xh, cnt);
  build_k<<<(E + 255) / 256, 256, 0, stream>>>(src, dst, cnt, csr, E);
  aggb_k<false><<<1250, 256, 0, stream>>>(xh, cnt, csr, nullptr, axh, nullptr);
  gemmthin_k<F, H, true><<<dim3(MP / 16, 4), 256, 0, stream>>>(axh, W1t, b1, h1h);
  gemmthin_k<H, F, false><<<dim3(MP / 16, 2), 256, 0, stream>>>(h1h, W2t, nullptr, xw2h);
  aggb_k<true><<<1250, 256, 0, stream>>>(xw2h, cnt, csr, b2, nullptr, (float*)d_out);
}